// Round 10
// baseline (75.737 us; speedup 1.0000x reference)
//
#include <hip/hip_runtime.h>
#include <math.h>

#define DIM   64
#define HID   512
#define BATCH 8192
#define R     2      // batch rows per wave
#define REC   1536   // floats per interleaved step record: [mu 512 | alpha 512 | w1 512]

// d_ws layout (floats)
#define W2SUM_OFF (64 * REC)          // 98304: [HID] col sums of alpha-block rows
#define B2SUM_OFF (W2SUM_OFF + HID)   // scalar sum b2[DIM..2*DIM-1]
#define WS_FLOATS (B2SUM_OFF + 1)

typedef float f32x4 __attribute__((ext_vector_type(4)));
typedef float f32x2 __attribute__((ext_vector_type(2)));

__global__ void prep_kernel(const float* __restrict__ W1,
                            const float* __restrict__ mask1,
                            const float* __restrict__ W2,
                            const float* __restrict__ mask2,
                            const float* __restrict__ b2,
                            float* __restrict__ ws) {
    int t = blockIdx.x * blockDim.x + threadIdx.x;
    const int nrec = 64 * REC;  // 98304
    if (t < nrec) {
        int rec = t / REC;
        int pos = t - rec * REC;
        float v;
        if (pos < HID) {                       // mu row i = mask2[i]*W2[i]
            int j = pos;
            v = mask2[rec * HID + j] * W2[rec * HID + j];
        } else if (pos < 2 * HID) {            // alpha row = mask2[64+i]*W2[64+i]
            int j = pos - HID;
            v = mask2[(DIM + rec) * HID + j] * W2[(DIM + rec) * HID + j];
        } else {                               // w1 col i (transposed masked W1)
            int j = pos - 2 * HID;
            v = mask1[j * DIM + rec] * W1[j * DIM + rec];
        }
        ws[t] = v;
    } else if (t < nrec + HID) {
        int j = t - nrec;
        float s = 0.f;
        for (int r = 0; r < DIM; ++r) {
            int idx = (DIM + r) * HID + j;
            s += mask2[idx] * W2[idx];
        }
        ws[W2SUM_OFF + j] = s;
    } else if (t == nrec + HID) {
        float s = 0.f;
        for (int r = 0; r < DIM; ++r) s += b2[DIM + r];
        ws[B2SUM_OFF] = s;
    }
}

// Full-wave (64-lane) sum via DPP, VALU-only. Result valid in lane 63.
__device__ __forceinline__ float wave_sum_dpp(float x) {
    x += __int_as_float(__builtin_amdgcn_update_dpp(0, __float_as_int(x), 0x111, 0xf, 0xf, true)); // row_shr:1
    x += __int_as_float(__builtin_amdgcn_update_dpp(0, __float_as_int(x), 0x112, 0xf, 0xf, true)); // row_shr:2
    x += __int_as_float(__builtin_amdgcn_update_dpp(0, __float_as_int(x), 0x114, 0xf, 0xf, true)); // row_shr:4
    x += __int_as_float(__builtin_amdgcn_update_dpp(0, __float_as_int(x), 0x118, 0xf, 0xf, true)); // row_shr:8
    x += __int_as_float(__builtin_amdgcn_update_dpp(0, __float_as_int(x), 0x142, 0xa, 0xf, true)); // row_bcast:15
    x += __int_as_float(__builtin_amdgcn_update_dpp(0, __float_as_int(x), 0x143, 0xc, 0xf, true)); // row_bcast:31
    return x;
}

__device__ __forceinline__ float readlane_f(float v, int lane) {
    return __int_as_float(__builtin_amdgcn_readlane(__float_as_int(v), lane));
}

// one 64-lane wave per R batch rows; lane L holds h[r] = pre-activations 8L..8L+7
__global__ __launch_bounds__(256, 4) void maf_kernel(
    const float* __restrict__ z,
    const float* __restrict__ b1,
    const float* __restrict__ b2,
    const float* __restrict__ ws,
    float* __restrict__ out) {
    const int lane = threadIdx.x & 63;
    const int wid  = (blockIdx.x * blockDim.x + threadIdx.x) >> 6;
    const int b0   = wid * R;
    const f32x4 Z4 = {0.f, 0.f, 0.f, 0.f};

    f32x4 h[R][2];
    {
        f32x4 bv0 = *(const f32x4*)(b1 + lane * 8);
        f32x4 bv1 = *(const f32x4*)(b1 + lane * 8 + 4);
#pragma unroll
        for (int r = 0; r < R; ++r) { h[r][0] = bv0; h[r][1] = bv1; }
    }
    float zl[R];
#pragma unroll
    for (int r = 0; r < R; ++r) zl[r] = z[(b0 + r) * DIM + lane];
    const float b2lo = b2[lane];
    const float b2hi = b2[DIM + lane];
    float xm[R];
#pragma unroll
    for (int r = 0; r < R; ++r) xm[r] = 0.f;

// p points at the ALPHA section of a record (+lane*8); mu at -512, w1 at +512.
// All byte offsets (-2048..+2064) fit the 13-bit signed immediate.
#define LOADW(p, M0, M1, A0, A1, C0, C1)                                    \
    do {                                                                    \
        M0 = *(const f32x4*)((p) - 512); M1 = *(const f32x4*)((p) - 508);   \
        A0 = *(const f32x4*)(p);         A1 = *(const f32x4*)((p) + 4);     \
        C0 = *(const f32x4*)((p) + 512); C1 = *(const f32x4*)((p) + 516);   \
    } while (0)

#define STEP(i, M0, M1, A0, A1, C0, C1)                                     \
    do {                                                                    \
        float _pm[R], _pa[R];                                               \
        _Pragma("unroll")                                                   \
        for (int r = 0; r < R; ++r) {                                       \
            f32x4 r0 = __builtin_elementwise_max(h[r][0], Z4);              \
            f32x4 r1 = __builtin_elementwise_max(h[r][1], Z4);              \
            f32x4 am = r0 * M0 + r1 * M1;                                   \
            f32x4 aa = r0 * A0 + r1 * A1;                                   \
            f32x2 tm = __builtin_shufflevector(am, am, 0, 1)                \
                     + __builtin_shufflevector(am, am, 2, 3);               \
            f32x2 ta = __builtin_shufflevector(aa, aa, 0, 1)                \
                     + __builtin_shufflevector(aa, aa, 2, 3);               \
            _pm[r] = wave_sum_dpp(tm.x + tm.y);                             \
            _pa[r] = wave_sum_dpp(ta.x + ta.y);                             \
        }                                                                   \
        const float _b2i  = readlane_f(b2lo, (i));                          \
        const float _b2di = readlane_f(b2hi, (i));                          \
        const bool  _at   = (lane == (i));                                  \
        _Pragma("unroll")                                                   \
        for (int r = 0; r < R; ++r) {                                       \
            const float _zi = readlane_f(zl[r], (i));                       \
            float _xv = _zi * __expf(_pa[r] + _b2di) + (_pm[r] + _b2i);     \
            const float _xs = readlane_f(_xv, 63);                          \
            if (_at) xm[r] = _xs;                                           \
            h[r][0] += C0 * _xs;                                            \
            h[r][1] += C1 * _xs;                                            \
        }                                                                   \
    } while (0)

    f32x4 m0A, m1A, a0A, a1A, c0A, c1A;
    f32x4 m0B, m1B, a0B, a1B, c0B, c1B;

    const float* wp = ws + HID + lane * 8;   // record 0, alpha section
    LOADW(wp, m0A, m1A, a0A, a1A, c0A, c1A); // step 0
    wp += REC;                               // -> record 1

#pragma unroll 1
    for (int i = 0; i < 62; i += 2) {
        LOADW(wp, m0B, m1B, a0B, a1B, c0B, c1B);     // step i+1
        __builtin_amdgcn_s_barrier();                // keep 4 waves aligned for L1 reuse
        STEP(i, m0A, m1A, a0A, a1A, c0A, c1A);
        const float* wq = wp + REC;
        LOADW(wq, m0A, m1A, a0A, a1A, c0A, c1A);     // step i+2
        STEP(i + 1, m0B, m1B, a0B, a1B, c0B, c1B);
        wp = wq + REC;
    }
    // A holds step 62; wp -> record 63
    LOADW(wp, m0B, m1B, a0B, a1B, c0B, c1B);
    STEP(62, m0A, m1A, a0A, a1A, c0A, c1A);
    STEP(63, m0B, m1B, a0B, a1B, c0B, c1B);

    // epilogue: x writes + log-det
    const float* w2s = ws + W2SUM_OFF;
    f32x4 s0 = *(const f32x4*)(w2s + lane * 8);
    f32x4 s1 = *(const f32x4*)(w2s + lane * 8 + 4);
    const float bsum = ws[B2SUM_OFF];
#pragma unroll
    for (int r = 0; r < R; ++r) {
        out[(b0 + r) * DIM + lane] = xm[r];
        f32x4 acc = __builtin_elementwise_max(h[r][0], Z4) * s0
                  + __builtin_elementwise_max(h[r][1], Z4) * s1;
        f32x2 t = __builtin_shufflevector(acc, acc, 0, 1)
                + __builtin_shufflevector(acc, acc, 2, 3);
        float pl = wave_sum_dpp(t.x + t.y);
        if (lane == 63) out[BATCH * DIM + b0 + r] = pl + bsum;
    }
#undef LOADW
#undef STEP
}

extern "C" void kernel_launch(void* const* d_in, const int* in_sizes, int n_in,
                              void* d_out, int out_size, void* d_ws, size_t ws_size,
                              hipStream_t stream) {
    const float* z     = (const float*)d_in[0];
    const float* W1    = (const float*)d_in[1];
    const float* b1    = (const float*)d_in[2];
    const float* W2    = (const float*)d_in[3];
    const float* b2    = (const float*)d_in[4];
    const float* mask1 = (const float*)d_in[5];
    const float* mask2 = (const float*)d_in[6];
    float* out = (float*)d_out;
    float* ws  = (float*)d_ws;

    {
        int total  = WS_FLOATS;
        int blocks = (total + 255) / 256;
        prep_kernel<<<blocks, 256, 0, stream>>>(W1, mask1, W2, mask2, b2, ws);
    }
    {
        int threads = 256;                 // 4 waves/block, R rows each
        int blocks  = BATCH / (R * 4);     // 1024 blocks -> 4 blocks/CU, 4 waves/SIMD
        maf_kernel<<<blocks, threads, 0, stream>>>(z, b1, b2, ws, out);
    }
}